// Round 1
// baseline (2419.068 us; speedup 1.0000x reference)
//
#include <hip/hip_runtime.h>

#define NN 100000
#define DD 128

// ---------------- degree / norm ----------------
__global__ void k_deg_init(float* deg, int n) {
    int v = blockIdx.x * blockDim.x + threadIdx.x;
    if (v < n) deg[v] = 1.0f;   // self-loop
}

__global__ void k_deg_count(const int* __restrict__ col, float* deg, int E) {
    int e = blockIdx.x * blockDim.x + threadIdx.x;
    if (e < E) atomicAdd(&deg[col[e]], 1.0f);
}

__global__ void k_deg_fin(float* deg, int n) {
    int v = blockIdx.x * blockDim.x + threadIdx.x;
    if (v < n) deg[v] = rsqrtf(deg[v]);   // deg >= 1 always
}

// ---------------- fp32 GEMM: Y = X @ W^T  (K = cols = 128) ----------------
// block: 256 threads, tile 64 nodes x 128 cols, thread tile 8 nodes x 4 cols
__global__ __launch_bounds__(256) void k_gemm(const float* __restrict__ X,
                                              const float* __restrict__ W,
                                              float* __restrict__ Y, int nrows) {
    __shared__ float Xst[32][64 + 4];    // Xst[kk][i]  (transposed X tile)
    __shared__ float Wt[32][DD + 4];     // Wt[kk][j]   (transposed W tile)
    int t  = threadIdx.x;
    int tx = t & 31;          // col group: j0 = tx*4
    int ty = t >> 5;          // node group: i0 = ty*8
    int i0 = ty * 8, j0 = tx * 4;
    long base = (long)blockIdx.x * 64;

    float acc[8][4] = {};

    for (int k0 = 0; k0 < 128; k0 += 32) {
        // Wt[kk][j] = W[j*128 + k0 + kk]; 4096 elems / 256 thr = 16 each (coalesced in kk)
        #pragma unroll
        for (int rep = 0; rep < 16; ++rep) {
            int idx = rep * 256 + t;
            int kk = idx & 31, j = idx >> 5;
            Wt[kk][j] = W[j * 128 + k0 + kk];
        }
        // Xst[kk][i] = X[(base+i)*128 + k0 + kk]; 2048 elems / 256 thr = 8 each
        #pragma unroll
        for (int rep = 0; rep < 8; ++rep) {
            int idx = rep * 256 + t;
            int kk = idx & 31, i = idx >> 5;
            long gi = base + i;
            Xst[kk][i] = (gi < nrows) ? X[gi * 128 + k0 + kk] : 0.0f;
        }
        __syncthreads();

        #pragma unroll
        for (int kk = 0; kk < 32; ++kk) {
            float4 w4 = *(const float4*)&Wt[kk][j0];
            float xs[8];
            *(float4*)&xs[0] = *(const float4*)&Xst[kk][i0];
            *(float4*)&xs[4] = *(const float4*)&Xst[kk][i0 + 4];
            #pragma unroll
            for (int a = 0; a < 8; ++a) {
                acc[a][0] += xs[a] * w4.x;
                acc[a][1] += xs[a] * w4.y;
                acc[a][2] += xs[a] * w4.z;
                acc[a][3] += xs[a] * w4.w;
            }
        }
        __syncthreads();
    }

    #pragma unroll
    for (int a = 0; a < 8; ++a) {
        long gi = base + i0 + a;
        if (gi < nrows)
            *(float4*)&Y[gi * 128 + j0] = *(const float4*)&acc[a][0];
    }
}

// ---------------- edge scatter: out[col] += dis[row]*dis[col] * xw[row] ----------------
// 32 lanes per edge, 4 features per lane (float4)
__global__ __launch_bounds__(256) void k_scatter(const int* __restrict__ row,
                                                 const int* __restrict__ col,
                                                 const float* __restrict__ dis,
                                                 const float* __restrict__ xw,
                                                 float* __restrict__ out, int E) {
    int e = blockIdx.x * 8 + (threadIdx.x >> 5);
    if (e >= E) return;
    int c  = (threadIdx.x & 31) * 4;
    int r  = row[e], cl = col[e];
    float nrm = dis[r] * dis[cl];
    float4 v = *(const float4*)&xw[(long)r * 128 + c];
    float* o = &out[(long)cl * 128 + c];
    atomicAdd(o + 0, nrm * v.x);
    atomicAdd(o + 1, nrm * v.y);
    atomicAdd(o + 2, nrm * v.z);
    atomicAdd(o + 3, nrm * v.w);
}

// ---------------- finalize: out = relu(out + dis^2 * xw + b) ----------------
__global__ __launch_bounds__(256) void k_finalize(float* __restrict__ out,
                                                  const float* __restrict__ xw,
                                                  const float* __restrict__ dis,
                                                  const float* __restrict__ b, int n) {
    long i = (long)blockIdx.x * blockDim.x + threadIdx.x;   // one float4 per thread
    if (i >= (long)n * 32) return;
    int node = (int)(i >> 5);
    int c = ((int)i & 31) * 4;
    float ds = dis[node];
    float s  = ds * ds;
    float4 a  = *(const float4*)&out[(long)node * 128 + c];
    float4 x  = *(const float4*)&xw[(long)node * 128 + c];
    float4 bb = *(const float4*)&b[c];
    float4 r;
    r.x = fmaxf(a.x + s * x.x + bb.x, 0.0f);
    r.y = fmaxf(a.y + s * x.y + bb.y, 0.0f);
    r.z = fmaxf(a.z + s * x.z + bb.z, 0.0f);
    r.w = fmaxf(a.w + s * x.w + bb.w, 0.0f);
    *(float4*)&out[(long)node * 128 + c] = r;
}

extern "C" void kernel_launch(void* const* d_in, const int* in_sizes, int n_in,
                              void* d_out, int out_size, void* d_ws, size_t ws_size,
                              hipStream_t stream) {
    const float* X  = (const float*)d_in[0];
    const float* W1 = (const float*)d_in[1];
    const float* b1 = (const float*)d_in[2];
    const float* W2 = (const float*)d_in[3];
    const float* b2 = (const float*)d_in[4];
    const int*   ei = (const int*)d_in[5];
    const int N = in_sizes[0] / DD;          // 100000
    const int E = in_sizes[5] / 2;           // 640000
    const int* row = ei;                     // edge_index[0]
    const int* col = ei + E;                 // edge_index[1]

    float* dis = (float*)d_ws;                       // N floats
    float* xw  = dis + ((N + 255) & ~255);           // N*DD floats (16B aligned)
    float* out = (float*)d_out;

    const int B = 256;
    // degree / dis (shared by both layers)
    k_deg_init<<<(N + B - 1) / B, B, 0, stream>>>(dis, N);
    k_deg_count<<<(E + B - 1) / B, B, 0, stream>>>(col, dis, E);
    k_deg_fin<<<(N + B - 1) / B, B, 0, stream>>>(dis, N);

    int gemm_grid = (N + 63) / 64;

    // ---- layer 1 ----
    k_gemm<<<gemm_grid, B, 0, stream>>>(X, W1, xw, N);
    hipMemsetAsync(d_out, 0, (size_t)N * DD * sizeof(float), stream);
    k_scatter<<<(E + 7) / 8, B, 0, stream>>>(row, col, dis, xw, out, E);
    k_finalize<<<((long)N * 32 + B - 1) / B, B, 0, stream>>>(out, xw, dis, b1, N);

    // ---- layer 2 ----  (reads h1 from d_out into xw, then reuses d_out as agg)
    k_gemm<<<gemm_grid, B, 0, stream>>>(out, W2, xw, N);
    hipMemsetAsync(d_out, 0, (size_t)N * DD * sizeof(float), stream);
    k_scatter<<<(E + 7) / 8, B, 0, stream>>>(row, col, dis, xw, out, E);
    k_finalize<<<((long)N * 32 + B - 1) / B, B, 0, stream>>>(out, xw, dis, b2, N);
}

// Round 2
// 626.545 us; speedup vs baseline: 3.8610x; 3.8610x over previous
//
#include <hip/hip_runtime.h>

#define DD 128

// ---------------- edge count: cnt[v] = #(col==v) (self-loops handled analytically) ----
__global__ void k_count(const int* __restrict__ col, int* __restrict__ cnt, int E) {
    int e = blockIdx.x * blockDim.x + threadIdx.x;
    if (e < E) atomicAdd(&cnt[col[e]], 1);
}

// ---------------- single-block scan: rowptr/cursor = exclusive_scan(cnt); dis = rsqrt(cnt+1) ----
__global__ __launch_bounds__(1024) void k_scan(const int* __restrict__ cnt,
                                               int* __restrict__ rowptr,
                                               int* __restrict__ cursor,
                                               float* __restrict__ dis, int n) {
    __shared__ int sums[1024];
    int t = threadIdx.x;
    int chunk = (n + 1023) / 1024;
    int s0 = t * chunk;
    int s1 = s0 + chunk; if (s1 > n) s1 = n;
    int sum = 0;
    for (int i = s0; i < s1; ++i) sum += cnt[i];
    sums[t] = sum;
    __syncthreads();
    // inclusive Hillis-Steele scan over 1024 partials
    for (int off = 1; off < 1024; off <<= 1) {
        int v = (t >= off) ? sums[t - off] : 0;
        __syncthreads();
        sums[t] += v;
        __syncthreads();
    }
    int base = (t == 0) ? 0 : sums[t - 1];
    for (int i = s0; i < s1; ++i) {
        int c = cnt[i];
        rowptr[i] = base;
        cursor[i] = base;
        dis[i] = rsqrtf((float)c + 1.0f);   // +1 for self-loop
        base += c;
    }
    if (t == 1023) rowptr[n] = base;
}

// ---------------- permute edges into col-grouped order ----------------
__global__ void k_permute(const int* __restrict__ row, const int* __restrict__ col,
                          const float* __restrict__ dis, int* __restrict__ cursor,
                          int* __restrict__ srow, float* __restrict__ snorm, int E) {
    int e = blockIdx.x * blockDim.x + threadIdx.x;
    if (e >= E) return;
    int r = row[e], c = col[e];
    int p = atomicAdd(&cursor[c], 1);
    srow[p]  = r;
    snorm[p] = dis[r] * dis[c];
}

// ---------------- fp32 GEMM: Y = X @ W^T  (K = 128) ----------------
__global__ __launch_bounds__(256) void k_gemm(const float* __restrict__ X,
                                              const float* __restrict__ W,
                                              float* __restrict__ Y, int nrows) {
    __shared__ float Xst[32][64 + 4];
    __shared__ float Wt[32][DD + 4];
    int t  = threadIdx.x;
    int tx = t & 31;
    int ty = t >> 5;
    int i0 = ty * 8, j0 = tx * 4;
    long base = (long)blockIdx.x * 64;

    float acc[8][4] = {};

    for (int k0 = 0; k0 < 128; k0 += 32) {
        #pragma unroll
        for (int rep = 0; rep < 16; ++rep) {
            int idx = rep * 256 + t;
            int kk = idx & 31, j = idx >> 5;
            Wt[kk][j] = W[j * 128 + k0 + kk];
        }
        #pragma unroll
        for (int rep = 0; rep < 8; ++rep) {
            int idx = rep * 256 + t;
            int kk = idx & 31, i = idx >> 5;
            long gi = base + i;
            Xst[kk][i] = (gi < nrows) ? X[gi * 128 + k0 + kk] : 0.0f;
        }
        __syncthreads();

        #pragma unroll
        for (int kk = 0; kk < 32; ++kk) {
            float4 w4 = *(const float4*)&Wt[kk][j0];
            float xs[8];
            *(float4*)&xs[0] = *(const float4*)&Xst[kk][i0];
            *(float4*)&xs[4] = *(const float4*)&Xst[kk][i0 + 4];
            #pragma unroll
            for (int a = 0; a < 8; ++a) {
                acc[a][0] += xs[a] * w4.x;
                acc[a][1] += xs[a] * w4.y;
                acc[a][2] += xs[a] * w4.z;
                acc[a][3] += xs[a] * w4.w;
            }
        }
        __syncthreads();
    }

    #pragma unroll
    for (int a = 0; a < 8; ++a) {
        long gi = base + i0 + a;
        if (gi < nrows)
            *(float4*)&Y[gi * 128 + j0] = *(const float4*)&acc[a][0];
    }
}

// ---------------- gather-aggregate + self-loop + bias + relu ----------------
// 32 lanes per node, float4 per lane
__global__ __launch_bounds__(256) void k_agg(const int* __restrict__ rowptr,
                                             const int* __restrict__ srow,
                                             const float* __restrict__ snorm,
                                             const float* __restrict__ dis,
                                             const float* __restrict__ xw,
                                             const float* __restrict__ b,
                                             float* __restrict__ out, int n) {
    int v = blockIdx.x * 8 + (threadIdx.x >> 5);
    if (v >= n) return;
    int c = (threadIdx.x & 31) * 4;

    float dv = dis[v];
    float s  = dv * dv;
    float4 acc = *(const float4*)&xw[(long)v * 128 + c];
    acc.x *= s; acc.y *= s; acc.z *= s; acc.w *= s;

    int e0 = rowptr[v], e1 = rowptr[v + 1];
    for (int e = e0; e < e1; ++e) {
        int   r  = srow[e];
        float nm = snorm[e];
        float4 xv = *(const float4*)&xw[(long)r * 128 + c];
        acc.x += nm * xv.x;
        acc.y += nm * xv.y;
        acc.z += nm * xv.z;
        acc.w += nm * xv.w;
    }

    float4 bb = *(const float4*)&b[c];
    float4 rr;
    rr.x = fmaxf(acc.x + bb.x, 0.0f);
    rr.y = fmaxf(acc.y + bb.y, 0.0f);
    rr.z = fmaxf(acc.z + bb.z, 0.0f);
    rr.w = fmaxf(acc.w + bb.w, 0.0f);
    *(float4*)&out[(long)v * 128 + c] = rr;
}

extern "C" void kernel_launch(void* const* d_in, const int* in_sizes, int n_in,
                              void* d_out, int out_size, void* d_ws, size_t ws_size,
                              hipStream_t stream) {
    const float* X  = (const float*)d_in[0];
    const float* W1 = (const float*)d_in[1];
    const float* b1 = (const float*)d_in[2];
    const float* W2 = (const float*)d_in[3];
    const float* b2 = (const float*)d_in[4];
    const int*   ei = (const int*)d_in[5];
    const int N = in_sizes[0] / DD;          // 100000
    const int E = in_sizes[5] / 2;           // 640000
    const int* row = ei;
    const int* col = ei + E;

    // -------- workspace carve-up (16B aligned chunks) --------
    char* p = (char*)d_ws;
    auto carve = [&](size_t bytes) { char* q = p; p += (bytes + 255) & ~(size_t)255; return q; };
    int*   cnt    = (int*)  carve((size_t)N * 4);
    int*   rowptr = (int*)  carve((size_t)(N + 1) * 4);
    int*   cursor = (int*)  carve((size_t)N * 4);
    int*   srow   = (int*)  carve((size_t)E * 4);
    float* snorm  = (float*)carve((size_t)E * 4);
    float* dis    = (float*)carve((size_t)N * 4);
    float* xw     = (float*)carve((size_t)N * DD * 4);
    float* out    = (float*)d_out;

    const int B = 256;

    // -------- CSR build (shared by both layers) --------
    hipMemsetAsync(cnt, 0, (size_t)N * 4, stream);
    k_count<<<(E + B - 1) / B, B, 0, stream>>>(col, cnt, E);
    k_scan<<<1, 1024, 0, stream>>>(cnt, rowptr, cursor, dis, N);
    k_permute<<<(E + B - 1) / B, B, 0, stream>>>(row, col, dis, cursor, srow, snorm, E);

    int gemm_grid = (N + 63) / 64;
    int agg_grid  = (N + 7) / 8;

    // ---- layer 1 ----
    k_gemm<<<gemm_grid, B, 0, stream>>>(X, W1, xw, N);
    k_agg<<<agg_grid, B, 0, stream>>>(rowptr, srow, snorm, dis, xw, b1, out, N);

    // ---- layer 2 ----
    k_gemm<<<gemm_grid, B, 0, stream>>>(out, W2, xw, N);
    k_agg<<<agg_grid, B, 0, stream>>>(rowptr, srow, snorm, dis, xw, b2, out, N);
}

// Round 3
// 352.804 us; speedup vs baseline: 6.8567x; 1.7759x over previous
//
#include <hip/hip_runtime.h>

#define DD 128

// ---------------- edge count: cnt[v] = #(col==v) ----------------
__global__ void k_count(const int* __restrict__ col, int* __restrict__ cnt, int E) {
    int e = blockIdx.x * blockDim.x + threadIdx.x;
    if (e < E) atomicAdd(&cnt[col[e]], 1);
}

// ---------------- scan phase 1: per-block sums (256 elems/block) ----------------
__global__ __launch_bounds__(256) void k_part(const int* __restrict__ cnt,
                                              int* __restrict__ part, int n) {
    __shared__ int s[256];
    int t = threadIdx.x;
    int i = blockIdx.x * 256 + t;
    s[t] = (i < n) ? cnt[i] : 0;
    __syncthreads();
    for (int off = 128; off > 0; off >>= 1) {
        if (t < off) s[t] += s[t + off];
        __syncthreads();
    }
    if (t == 0) part[blockIdx.x] = s[0];
}

// ---------------- scan phase 2: single block scans the partials (exclusive) ----------------
__global__ __launch_bounds__(1024) void k_scanpart(int* __restrict__ part, int nblk) {
    __shared__ int s[1024];
    int t = threadIdx.x;
    int v = (t < nblk) ? part[t] : 0;
    s[t] = v;
    __syncthreads();
    for (int off = 1; off < 1024; off <<= 1) {
        int u = (t >= off) ? s[t - off] : 0;
        __syncthreads();
        s[t] += u;
        __syncthreads();
    }
    if (t < nblk) part[t] = s[t] - v;   // exclusive
}

// ---------------- scan phase 3: per-block scan + apply; writes rowptr/cursor/dis ----------------
__global__ __launch_bounds__(256) void k_apply(const int* __restrict__ cnt,
                                               const int* __restrict__ part,
                                               int* __restrict__ rowptr,
                                               int* __restrict__ cursor,
                                               float* __restrict__ dis, int n) {
    __shared__ int s[256];
    int t = threadIdx.x;
    int i = blockIdx.x * 256 + t;
    int c = (i < n) ? cnt[i] : 0;
    s[t] = c;
    __syncthreads();
    for (int off = 1; off < 256; off <<= 1) {
        int u = (t >= off) ? s[t - off] : 0;
        __syncthreads();
        s[t] += u;
        __syncthreads();
    }
    int base = part[blockIdx.x] + s[t] - c;   // exclusive prefix
    if (i < n) {
        rowptr[i] = base;
        cursor[i] = base;
        dis[i] = rsqrtf((float)c + 1.0f);
        if (i == n - 1) rowptr[n] = base + c;
    }
}

// ---------------- permute edges into col-grouped order ----------------
__global__ void k_permute(const int* __restrict__ row, const int* __restrict__ col,
                          const float* __restrict__ dis, int* __restrict__ cursor,
                          int* __restrict__ srow, float* __restrict__ snorm, int E) {
    int e = blockIdx.x * blockDim.x + threadIdx.x;
    if (e >= E) return;
    int r = row[e], c = col[e];
    int p = atomicAdd(&cursor[c], 1);
    srow[p]  = r;
    snorm[p] = dis[r] * dis[c];
}

// ---------------- fp32 GEMM: Y = X @ W^T  (K = 128) ----------------
__global__ __launch_bounds__(256) void k_gemm(const float* __restrict__ X,
                                              const float* __restrict__ W,
                                              float* __restrict__ Y, int nrows) {
    __shared__ float Xst[32][64 + 4];
    __shared__ float Wt[32][DD + 4];
    int t  = threadIdx.x;
    int tx = t & 31;
    int ty = t >> 5;
    int i0 = ty * 8, j0 = tx * 4;
    long base = (long)blockIdx.x * 64;

    float acc[8][4] = {};

    for (int k0 = 0; k0 < 128; k0 += 32) {
        #pragma unroll
        for (int rep = 0; rep < 16; ++rep) {
            int idx = rep * 256 + t;
            int kk = idx & 31, j = idx >> 5;
            Wt[kk][j] = W[j * 128 + k0 + kk];
        }
        #pragma unroll
        for (int rep = 0; rep < 8; ++rep) {
            int idx = rep * 256 + t;
            int kk = idx & 31, i = idx >> 5;
            long gi = base + i;
            Xst[kk][i] = (gi < nrows) ? X[gi * 128 + k0 + kk] : 0.0f;
        }
        __syncthreads();

        #pragma unroll
        for (int kk = 0; kk < 32; ++kk) {
            float4 w4 = *(const float4*)&Wt[kk][j0];
            float xs[8];
            *(float4*)&xs[0] = *(const float4*)&Xst[kk][i0];
            *(float4*)&xs[4] = *(const float4*)&Xst[kk][i0 + 4];
            #pragma unroll
            for (int a = 0; a < 8; ++a) {
                acc[a][0] += xs[a] * w4.x;
                acc[a][1] += xs[a] * w4.y;
                acc[a][2] += xs[a] * w4.z;
                acc[a][3] += xs[a] * w4.w;
            }
        }
        __syncthreads();
    }

    #pragma unroll
    for (int a = 0; a < 8; ++a) {
        long gi = base + i0 + a;
        if (gi < nrows)
            *(float4*)&Y[gi * 128 + j0] = *(const float4*)&acc[a][0];
    }
}

// ---------------- gather-aggregate + self-loop + bias + relu ----------------
// 32 lanes per node, float4 per lane
__global__ __launch_bounds__(256) void k_agg(const int* __restrict__ rowptr,
                                             const int* __restrict__ srow,
                                             const float* __restrict__ snorm,
                                             const float* __restrict__ dis,
                                             const float* __restrict__ xw,
                                             const float* __restrict__ b,
                                             float* __restrict__ out, int n) {
    int v = blockIdx.x * 8 + (threadIdx.x >> 5);
    if (v >= n) return;
    int c = (threadIdx.x & 31) * 4;

    float dv = dis[v];
    float s  = dv * dv;
    float4 acc = *(const float4*)&xw[(long)v * 128 + c];
    acc.x *= s; acc.y *= s; acc.z *= s; acc.w *= s;

    int e0 = rowptr[v], e1 = rowptr[v + 1];
    for (int e = e0; e < e1; ++e) {
        int   r  = srow[e];
        float nm = snorm[e];
        float4 xv = *(const float4*)&xw[(long)r * 128 + c];
        acc.x += nm * xv.x;
        acc.y += nm * xv.y;
        acc.z += nm * xv.z;
        acc.w += nm * xv.w;
    }

    float4 bb = *(const float4*)&b[c];
    float4 rr;
    rr.x = fmaxf(acc.x + bb.x, 0.0f);
    rr.y = fmaxf(acc.y + bb.y, 0.0f);
    rr.z = fmaxf(acc.z + bb.z, 0.0f);
    rr.w = fmaxf(acc.w + bb.w, 0.0f);
    *(float4*)&out[(long)v * 128 + c] = rr;
}

extern "C" void kernel_launch(void* const* d_in, const int* in_sizes, int n_in,
                              void* d_out, int out_size, void* d_ws, size_t ws_size,
                              hipStream_t stream) {
    const float* X  = (const float*)d_in[0];
    const float* W1 = (const float*)d_in[1];
    const float* b1 = (const float*)d_in[2];
    const float* W2 = (const float*)d_in[3];
    const float* b2 = (const float*)d_in[4];
    const int*   ei = (const int*)d_in[5];
    const int N = in_sizes[0] / DD;          // 100000
    const int E = in_sizes[5] / 2;           // 640000
    const int* row = ei;
    const int* col = ei + E;

    // -------- workspace carve-up --------
    char* p = (char*)d_ws;
    auto carve = [&](size_t bytes) { char* q = p; p += (bytes + 255) & ~(size_t)255; return q; };
    int*   cnt    = (int*)  carve((size_t)N * 4);
    int*   rowptr = (int*)  carve((size_t)(N + 1) * 4);
    int*   cursor = (int*)  carve((size_t)N * 4);
    int*   part   = (int*)  carve(1024 * 4);
    int*   srow   = (int*)  carve((size_t)E * 4);
    float* snorm  = (float*)carve((size_t)E * 4);
    float* dis    = (float*)carve((size_t)N * 4);
    float* xw     = (float*)carve((size_t)N * DD * 4);
    float* out    = (float*)d_out;

    const int B = 256;
    const int NBLK = (N + 255) / 256;   // 391

    // -------- CSR build (shared by both layers) --------
    hipMemsetAsync(cnt, 0, (size_t)N * 4, stream);
    k_count<<<(E + B - 1) / B, B, 0, stream>>>(col, cnt, E);
    k_part<<<NBLK, B, 0, stream>>>(cnt, part, N);
    k_scanpart<<<1, 1024, 0, stream>>>(part, NBLK);
    k_apply<<<NBLK, B, 0, stream>>>(cnt, part, rowptr, cursor, dis, N);
    k_permute<<<(E + B - 1) / B, B, 0, stream>>>(row, col, dis, cursor, srow, snorm, E);

    int gemm_grid = (N + 63) / 64;
    int agg_grid  = (N + 7) / 8;

    // ---- layer 1 ----
    k_gemm<<<gemm_grid, B, 0, stream>>>(X, W1, xw, N);
    k_agg<<<agg_grid, B, 0, stream>>>(rowptr, srow, snorm, dis, xw, b1, out, N);

    // ---- layer 2 ----
    k_gemm<<<gemm_grid, B, 0, stream>>>(out, W2, xw, N);
    k_agg<<<agg_grid, B, 0, stream>>>(rowptr, srow, snorm, dis, xw, b2, out, N);
}

// Round 4
// 188.075 us; speedup vs baseline: 12.8622x; 1.8759x over previous
//
#include <hip/hip_runtime.h>

#define DD 128

typedef short bf16x8 __attribute__((ext_vector_type(8)));
typedef float f32x4 __attribute__((ext_vector_type(4)));

__device__ __forceinline__ unsigned short f2bf(float f) {   // fp32 -> bf16, RNE
    unsigned int u = __builtin_bit_cast(unsigned int, f);
    u += 0x7fffu + ((u >> 16) & 1u);
    return (unsigned short)(u >> 16);
}
__device__ __forceinline__ float bflo(unsigned int u) { return __builtin_bit_cast(float, u << 16); }
__device__ __forceinline__ float bfhi(unsigned int u) { return __builtin_bit_cast(float, u & 0xffff0000u); }

// ---------------- CSR build ----------------
__global__ void k_count(const int* __restrict__ col, int* __restrict__ cnt, int E) {
    int e = blockIdx.x * blockDim.x + threadIdx.x;
    if (e < E) atomicAdd(&cnt[col[e]], 1);
}

__global__ __launch_bounds__(256) void k_part(const int* __restrict__ cnt,
                                              int* __restrict__ part, int n) {
    __shared__ int s[256];
    int t = threadIdx.x;
    int i = blockIdx.x * 256 + t;
    s[t] = (i < n) ? cnt[i] : 0;
    __syncthreads();
    for (int off = 128; off > 0; off >>= 1) {
        if (t < off) s[t] += s[t + off];
        __syncthreads();
    }
    if (t == 0) part[blockIdx.x] = s[0];
}

__global__ __launch_bounds__(1024) void k_scanpart(int* __restrict__ part, int nblk) {
    __shared__ int s[1024];
    int t = threadIdx.x;
    int v = (t < nblk) ? part[t] : 0;
    s[t] = v;
    __syncthreads();
    for (int off = 1; off < 1024; off <<= 1) {
        int u = (t >= off) ? s[t - off] : 0;
        __syncthreads();
        s[t] += u;
        __syncthreads();
    }
    if (t < nblk) part[t] = s[t] - v;   // exclusive
}

__global__ __launch_bounds__(256) void k_apply(const int* __restrict__ cnt,
                                               const int* __restrict__ part,
                                               int* __restrict__ rowptr,
                                               int* __restrict__ cursor,
                                               float* __restrict__ dis, int n) {
    __shared__ int s[256];
    int t = threadIdx.x;
    int i = blockIdx.x * 256 + t;
    int c = (i < n) ? cnt[i] : 0;
    s[t] = c;
    __syncthreads();
    for (int off = 1; off < 256; off <<= 1) {
        int u = (t >= off) ? s[t - off] : 0;
        __syncthreads();
        s[t] += u;
        __syncthreads();
    }
    int base = part[blockIdx.x] + s[t] - c;
    if (i < n) {
        rowptr[i] = base;
        cursor[i] = base;
        dis[i] = rsqrtf((float)c + 1.0f);
        if (i == n - 1) rowptr[n] = base + c;
    }
}

__global__ void k_permute(const int* __restrict__ row, const int* __restrict__ col,
                          const float* __restrict__ dis, int* __restrict__ cursor,
                          int* __restrict__ srow, float* __restrict__ snorm, int E) {
    int e = blockIdx.x * blockDim.x + threadIdx.x;
    if (e >= E) return;
    int r = row[e], c = col[e];
    int p = atomicAdd(&cursor[c], 1);
    srow[p]  = r;
    snorm[p] = dis[r] * dis[c];
}

// ---------------- MFMA GEMM: Y(bf16) = X @ W^T ----------------
// block = 256 (4 waves), 64 rows/block, wave = 16 rows x 128 cols.
// A-frag (16x32): lane l holds X[r0 + (l&15)][kc*32 + (l>>4)*8 .. +7]  (8 contiguous)
// B-frag (32x16): lane l holds W[jt*16 + (l&15)][kc*32 + (l>>4)*8 .. +7] (row of W = col of W^T)
// D: lane l, reg r -> C[r0 + (l>>4)*4 + r][jt*16 + (l&15)]
template <bool INBF16>
__global__ __launch_bounds__(256) void k_gemm_mfma(const void* __restrict__ Xv,
                                                   const float* __restrict__ W,
                                                   unsigned short* __restrict__ Y,
                                                   int nrows) {
    __shared__ unsigned short Ws[128 * 128];   // 32 KB, 16B-chunk XOR swizzle
    const int t = threadIdx.x;

    // stage W: fp32 -> bf16, swizzled. chunk' = chunk ^ (row & 15)
    #pragma unroll
    for (int i = 0; i < 8; ++i) {
        int g   = i * 256 + t;        // 16B-chunk id, 0..2047
        int row = g >> 4, ch = g & 15;
        const float* src = W + row * 128 + ch * 8;
        float4 f0 = *(const float4*)src;
        float4 f1 = *(const float4*)(src + 4);
        unsigned short u[8] = { f2bf(f0.x), f2bf(f0.y), f2bf(f0.z), f2bf(f0.w),
                                f2bf(f1.x), f2bf(f1.y), f2bf(f1.z), f2bf(f1.w) };
        int dst = row * 128 + ((ch ^ (row & 15)) << 3);
        *(uint4*)&Ws[dst] = *(const uint4*)u;
    }
    __syncthreads();

    const int wid  = t >> 6;
    const int lane = t & 63;
    const int lr   = lane & 15;
    const int lk   = lane >> 4;
    const long r0  = (long)blockIdx.x * 64 + wid * 16;

    long arow = r0 + lr;
    if (arow >= nrows) arow = nrows - 1;   // clamp (stores are guarded)

    f32x4 acc[8] = {};

    #pragma unroll
    for (int kc = 0; kc < 4; ++kc) {
        bf16x8 af;
        if (INBF16) {
            const unsigned short* ap = (const unsigned short*)Xv + arow * 128 + kc * 32 + lk * 8;
            af = *(const bf16x8*)ap;
        } else {
            const float* ap = (const float*)Xv + arow * 128 + kc * 32 + lk * 8;
            float4 a0 = *(const float4*)ap;
            float4 a1 = *(const float4*)(ap + 4);
            af[0] = (short)f2bf(a0.x); af[1] = (short)f2bf(a0.y);
            af[2] = (short)f2bf(a0.z); af[3] = (short)f2bf(a0.w);
            af[4] = (short)f2bf(a1.x); af[5] = (short)f2bf(a1.y);
            af[6] = (short)f2bf(a1.z); af[7] = (short)f2bf(a1.w);
        }
        #pragma unroll
        for (int jt = 0; jt < 8; ++jt) {
            int j  = jt * 16 + lr;
            int ch = (kc * 4 + lk) ^ lr;
            const bf16x8* bp = (const bf16x8*)&Ws[j * 128 + (ch << 3)];
            acc[jt] = __builtin_amdgcn_mfma_f32_16x16x32_bf16(af, *bp, acc[jt], 0, 0, 0);
        }
    }

    #pragma unroll
    for (int jt = 0; jt < 8; ++jt) {
        #pragma unroll
        for (int r = 0; r < 4; ++r) {
            long m = r0 + lk * 4 + r;
            if (m < nrows) Y[m * 128 + jt * 16 + lr] = f2bf(acc[jt][r]);
        }
    }
}

// ---------------- gather-aggregate + self-loop + bias + relu ----------------
// 16 lanes/node, 8 bf16 cols per lane (uint4 = 16B gather)
__device__ __forceinline__ void fma8(float* acc, float nm, uint4 q) {
    acc[0] += nm * bflo(q.x); acc[1] += nm * bfhi(q.x);
    acc[2] += nm * bflo(q.y); acc[3] += nm * bfhi(q.y);
    acc[4] += nm * bflo(q.z); acc[5] += nm * bfhi(q.z);
    acc[6] += nm * bflo(q.w); acc[7] += nm * bfhi(q.w);
}

template <bool OUTBF16>
__global__ __launch_bounds__(256) void k_agg(const int* __restrict__ rowptr,
                                             const int* __restrict__ srow,
                                             const float* __restrict__ snorm,
                                             const float* __restrict__ dis,
                                             const unsigned short* __restrict__ xw,
                                             const float* __restrict__ b,
                                             void* __restrict__ outv, int n) {
    int v = blockIdx.x * 16 + (threadIdx.x >> 4);
    if (v >= n) return;
    int c = (threadIdx.x & 15) * 8;

    float dv = dis[v], s = dv * dv;
    float acc[8] = {};
    fma8(acc, s, *(const uint4*)(xw + (long)v * 128 + c));   // self-loop term

    int e0 = rowptr[v], e1 = rowptr[v + 1];
    int e = e0;
    for (; e + 2 <= e1; e += 2) {
        int   r1 = srow[e],  r2 = srow[e + 1];
        float n1 = snorm[e], n2 = snorm[e + 1];
        uint4 q1 = *(const uint4*)(xw + (long)r1 * 128 + c);
        uint4 q2 = *(const uint4*)(xw + (long)r2 * 128 + c);
        fma8(acc, n1, q1);
        fma8(acc, n2, q2);
    }
    if (e < e1) {
        int   r1 = srow[e];
        float n1 = snorm[e];
        fma8(acc, n1, *(const uint4*)(xw + (long)r1 * 128 + c));
    }

    float4 b0 = *(const float4*)(b + c);
    float4 b1 = *(const float4*)(b + c + 4);
    float o[8];
    o[0] = fmaxf(acc[0] + b0.x, 0.0f); o[1] = fmaxf(acc[1] + b0.y, 0.0f);
    o[2] = fmaxf(acc[2] + b0.z, 0.0f); o[3] = fmaxf(acc[3] + b0.w, 0.0f);
    o[4] = fmaxf(acc[4] + b1.x, 0.0f); o[5] = fmaxf(acc[5] + b1.y, 0.0f);
    o[6] = fmaxf(acc[6] + b1.z, 0.0f); o[7] = fmaxf(acc[7] + b1.w, 0.0f);

    if (OUTBF16) {
        unsigned int p[4];
        p[0] = (unsigned int)f2bf(o[0]) | ((unsigned int)f2bf(o[1]) << 16);
        p[1] = (unsigned int)f2bf(o[2]) | ((unsigned int)f2bf(o[3]) << 16);
        p[2] = (unsigned int)f2bf(o[4]) | ((unsigned int)f2bf(o[5]) << 16);
        p[3] = (unsigned int)f2bf(o[6]) | ((unsigned int)f2bf(o[7]) << 16);
        *(uint4*)((unsigned short*)outv + (long)v * 128 + c) = *(const uint4*)p;
    } else {
        float* op = (float*)outv + (long)v * 128 + c;
        *(float4*)op       = make_float4(o[0], o[1], o[2], o[3]);
        *(float4*)(op + 4) = make_float4(o[4], o[5], o[6], o[7]);
    }
}

extern "C" void kernel_launch(void* const* d_in, const int* in_sizes, int n_in,
                              void* d_out, int out_size, void* d_ws, size_t ws_size,
                              hipStream_t stream) {
    const float* X  = (const float*)d_in[0];
    const float* W1 = (const float*)d_in[1];
    const float* b1 = (const float*)d_in[2];
    const float* W2 = (const float*)d_in[3];
    const float* b2 = (const float*)d_in[4];
    const int*   ei = (const int*)d_in[5];
    const int N = in_sizes[0] / DD;          // 100000
    const int E = in_sizes[5] / 2;           // 640000
    const int* row = ei;
    const int* col = ei + E;

    // -------- workspace carve-up --------
    char* p = (char*)d_ws;
    auto carve = [&](size_t bytes) { char* q = p; p += (bytes + 255) & ~(size_t)255; return q; };
    int*            cnt    = (int*)           carve((size_t)N * 4);
    int*            rowptr = (int*)           carve((size_t)(N + 1) * 4);
    int*            cursor = (int*)           carve((size_t)N * 4);
    int*            part   = (int*)           carve(1024 * 4);
    int*            srow   = (int*)           carve((size_t)E * 4);
    float*          snorm  = (float*)         carve((size_t)E * 4);
    float*          dis    = (float*)         carve((size_t)N * 4);
    unsigned short* xw     = (unsigned short*)carve((size_t)N * DD * 2);   // bf16
    unsigned short* h1     = (unsigned short*)d_out;                       // bf16 scratch in d_out

    const int B = 256;
    const int NBLK = (N + 255) / 256;

    // -------- CSR build (shared by both layers) --------
    hipMemsetAsync(cnt, 0, (size_t)N * 4, stream);
    k_count<<<(E + B - 1) / B, B, 0, stream>>>(col, cnt, E);
    k_part<<<NBLK, B, 0, stream>>>(cnt, part, N);
    k_scanpart<<<1, 1024, 0, stream>>>(part, NBLK);
    k_apply<<<NBLK, B, 0, stream>>>(cnt, part, rowptr, cursor, dis, N);
    k_permute<<<(E + B - 1) / B, B, 0, stream>>>(row, col, dis, cursor, srow, snorm, E);

    int gemm_grid = (N + 63) / 64;
    int agg_grid  = (N + 15) / 16;

    // ---- layer 1 ----
    k_gemm_mfma<false><<<gemm_grid, B, 0, stream>>>(X, W1, xw, N);
    k_agg<true><<<agg_grid, B, 0, stream>>>(rowptr, srow, snorm, dis, xw, b1, h1, N);

    // ---- layer 2 ----  (h1 bf16 lives in d_out; GEMM2 consumes it before AGG2 overwrites)
    k_gemm_mfma<true><<<gemm_grid, B, 0, stream>>>(h1, W2, xw, N);
    k_agg<false><<<agg_grid, B, 0, stream>>>(rowptr, srow, snorm, dis, xw, b2, d_out, N);
}

// Round 5
// 175.298 us; speedup vs baseline: 13.7997x; 1.0729x over previous
//
#include <hip/hip_runtime.h>

#define DD 128

typedef short bf16x8 __attribute__((ext_vector_type(8)));
typedef float f32x4 __attribute__((ext_vector_type(4)));

__device__ __forceinline__ unsigned short f2bf(float f) {   // fp32 -> bf16, RNE
    unsigned int u = __builtin_bit_cast(unsigned int, f);
    u += 0x7fffu + ((u >> 16) & 1u);
    return (unsigned short)(u >> 16);
}
__device__ __forceinline__ float bflo(unsigned int u) { return __builtin_bit_cast(float, u << 16); }
__device__ __forceinline__ float bfhi(unsigned int u) { return __builtin_bit_cast(float, u & 0xffff0000u); }

// ---------------- scan phases ----------------
__global__ __launch_bounds__(256) void k_part(const int* __restrict__ cnt,
                                              int* __restrict__ part, int n) {
    __shared__ int s[256];
    int t = threadIdx.x;
    int i = blockIdx.x * 256 + t;
    s[t] = (i < n) ? cnt[i] : 0;
    __syncthreads();
    for (int off = 128; off > 0; off >>= 1) {
        if (t < off) s[t] += s[t + off];
        __syncthreads();
    }
    if (t == 0) part[blockIdx.x] = s[0];
}

__global__ __launch_bounds__(1024) void k_scanpart(int* __restrict__ part, int nblk) {
    __shared__ int s[1024];
    int t = threadIdx.x;
    int v = (t < nblk) ? part[t] : 0;
    s[t] = v;
    __syncthreads();
    for (int off = 1; off < 1024; off <<= 1) {
        int u = (t >= off) ? s[t - off] : 0;
        __syncthreads();
        s[t] += u;
        __syncthreads();
    }
    if (t < nblk) part[t] = s[t] - v;   // exclusive
}

__global__ __launch_bounds__(256) void k_apply(const int* __restrict__ cnt,
                                               const int* __restrict__ part,
                                               int* __restrict__ rowptr,
                                               int* __restrict__ cursor,
                                               float* __restrict__ dis, int n) {
    __shared__ int s[256];
    int t = threadIdx.x;
    int i = blockIdx.x * 256 + t;
    int c = (i < n) ? cnt[i] : 0;
    s[t] = c;
    __syncthreads();
    for (int off = 1; off < 256; off <<= 1) {
        int u = (t >= off) ? s[t - off] : 0;
        __syncthreads();
        s[t] += u;
        __syncthreads();
    }
    int base = part[blockIdx.x] + s[t] - c;
    if (i < n) {
        rowptr[i] = base;
        cursor[i] = base;
        dis[i] = rsqrtf((float)c + 1.0f);
        if (i == n - 1) rowptr[n] = base + c;
    }
}

// ---------------- permute: srow only (norm recomputed in agg) ----------------
__global__ void k_permute(const int* __restrict__ row, const int* __restrict__ col,
                          int* __restrict__ cursor, int* __restrict__ srow, int E) {
    int e = blockIdx.x * blockDim.x + threadIdx.x;
    if (e >= E) return;
    int p = atomicAdd(&cursor[col[e]], 1);
    srow[p] = row[e];
}

// ---------------- MFMA GEMM: Y(bf16) = X @ W^T  (+ optional fused edge count) ----------------
// gemm blocks: [0, gemm_blocks); count blocks: [gemm_blocks, gemm_blocks + count_blocks)
template <bool INBF16, bool FUSE_COUNT>
__global__ __launch_bounds__(256) void k_gemm_mfma(const void* __restrict__ Xv,
                                                   const float* __restrict__ W,
                                                   unsigned short* __restrict__ Y,
                                                   int nrows, int gemm_blocks,
                                                   const int* __restrict__ col,
                                                   int* __restrict__ cnt, int E) {
    __shared__ unsigned short Ws[128 * 128];   // 32 KB, 16B-chunk XOR swizzle
    const int t = threadIdx.x;

    if (FUSE_COUNT && blockIdx.x >= gemm_blocks) {
        int e = (blockIdx.x - gemm_blocks) * 256 + t;
        if (e < E) atomicAdd(&cnt[col[e]], 1);
        return;
    }

    // stage W: fp32 -> bf16, swizzled. chunk' = chunk ^ (row & 15)
    #pragma unroll
    for (int i = 0; i < 8; ++i) {
        int g   = i * 256 + t;        // 16B-chunk id, 0..2047
        int row = g >> 4, ch = g & 15;
        const float* src = W + row * 128 + ch * 8;
        float4 f0 = *(const float4*)src;
        float4 f1 = *(const float4*)(src + 4);
        unsigned short u[8] = { f2bf(f0.x), f2bf(f0.y), f2bf(f0.z), f2bf(f0.w),
                                f2bf(f1.x), f2bf(f1.y), f2bf(f1.z), f2bf(f1.w) };
        int dst = row * 128 + ((ch ^ (row & 15)) << 3);
        *(uint4*)&Ws[dst] = *(const uint4*)u;
    }
    __syncthreads();

    const int wid  = t >> 6;
    const int lane = t & 63;
    const int lr   = lane & 15;
    const int lk   = lane >> 4;
    const long r0  = (long)blockIdx.x * 64 + wid * 16;

    long arow = r0 + lr;
    if (arow >= nrows) arow = nrows - 1;   // clamp (stores are guarded)

    f32x4 acc[8] = {};

    #pragma unroll
    for (int kc = 0; kc < 4; ++kc) {
        bf16x8 af;
        if (INBF16) {
            const unsigned short* ap = (const unsigned short*)Xv + arow * 128 + kc * 32 + lk * 8;
            af = *(const bf16x8*)ap;
        } else {
            const float* ap = (const float*)Xv + arow * 128 + kc * 32 + lk * 8;
            float4 a0 = *(const float4*)ap;
            float4 a1 = *(const float4*)(ap + 4);
            af[0] = (short)f2bf(a0.x); af[1] = (short)f2bf(a0.y);
            af[2] = (short)f2bf(a0.z); af[3] = (short)f2bf(a0.w);
            af[4] = (short)f2bf(a1.x); af[5] = (short)f2bf(a1.y);
            af[6] = (short)f2bf(a1.z); af[7] = (short)f2bf(a1.w);
        }
        #pragma unroll
        for (int jt = 0; jt < 8; ++jt) {
            int j  = jt * 16 + lr;
            int ch = (kc * 4 + lk) ^ lr;
            const bf16x8* bp = (const bf16x8*)&Ws[j * 128 + (ch << 3)];
            acc[jt] = __builtin_amdgcn_mfma_f32_16x16x32_bf16(af, *bp, acc[jt], 0, 0, 0);
        }
    }

    #pragma unroll
    for (int jt = 0; jt < 8; ++jt) {
        #pragma unroll
        for (int r = 0; r < 4; ++r) {
            long m = r0 + lk * 4 + r;
            if (m < nrows) Y[m * 128 + jt * 16 + lr] = f2bf(acc[jt][r]);
        }
    }
}

// ---------------- gather-aggregate + self-loop + bias + relu ----------------
// 16 lanes/node, 8 bf16 cols per lane (uint4 = 16B gather); norm computed in-loop
__device__ __forceinline__ void fma8(float* acc, float nm, uint4 q) {
    acc[0] += nm * bflo(q.x); acc[1] += nm * bfhi(q.x);
    acc[2] += nm * bflo(q.y); acc[3] += nm * bfhi(q.y);
    acc[4] += nm * bflo(q.z); acc[5] += nm * bfhi(q.z);
    acc[6] += nm * bflo(q.w); acc[7] += nm * bfhi(q.w);
}

template <bool OUTBF16>
__global__ __launch_bounds__(256) void k_agg(const int* __restrict__ rowptr,
                                             const int* __restrict__ srow,
                                             const float* __restrict__ dis,
                                             const unsigned short* __restrict__ xw,
                                             const float* __restrict__ b,
                                             void* __restrict__ outv, int n) {
    int v = blockIdx.x * 16 + (threadIdx.x >> 4);
    if (v >= n) return;
    int c = (threadIdx.x & 15) * 8;

    float dv = dis[v], s = dv * dv;
    float acc[8] = {};
    fma8(acc, s, *(const uint4*)(xw + (long)v * 128 + c));   // self-loop term

    int e0 = rowptr[v], e1 = rowptr[v + 1];
    int e = e0;
    for (; e + 2 <= e1; e += 2) {
        int   r1 = srow[e],  r2 = srow[e + 1];
        float n1 = dis[r1] * dv, n2 = dis[r2] * dv;
        uint4 q1 = *(const uint4*)(xw + (long)r1 * 128 + c);
        uint4 q2 = *(const uint4*)(xw + (long)r2 * 128 + c);
        fma8(acc, n1, q1);
        fma8(acc, n2, q2);
    }
    if (e < e1) {
        int   r1 = srow[e];
        float n1 = dis[r1] * dv;
        fma8(acc, n1, *(const uint4*)(xw + (long)r1 * 128 + c));
    }

    float4 b0 = *(const float4*)(b + c);
    float4 b1 = *(const float4*)(b + c + 4);
    float o[8];
    o[0] = fmaxf(acc[0] + b0.x, 0.0f); o[1] = fmaxf(acc[1] + b0.y, 0.0f);
    o[2] = fmaxf(acc[2] + b0.z, 0.0f); o[3] = fmaxf(acc[3] + b0.w, 0.0f);
    o[4] = fmaxf(acc[4] + b1.x, 0.0f); o[5] = fmaxf(acc[5] + b1.y, 0.0f);
    o[6] = fmaxf(acc[6] + b1.z, 0.0f); o[7] = fmaxf(acc[7] + b1.w, 0.0f);

    if (OUTBF16) {
        unsigned int p[4];
        p[0] = (unsigned int)f2bf(o[0]) | ((unsigned int)f2bf(o[1]) << 16);
        p[1] = (unsigned int)f2bf(o[2]) | ((unsigned int)f2bf(o[3]) << 16);
        p[2] = (unsigned int)f2bf(o[4]) | ((unsigned int)f2bf(o[5]) << 16);
        p[3] = (unsigned int)f2bf(o[6]) | ((unsigned int)f2bf(o[7]) << 16);
        *(uint4*)((unsigned short*)outv + (long)v * 128 + c) = *(const uint4*)p;
    } else {
        float* op = (float*)outv + (long)v * 128 + c;
        *(float4*)op       = make_float4(o[0], o[1], o[2], o[3]);
        *(float4*)(op + 4) = make_float4(o[4], o[5], o[6], o[7]);
    }
}

extern "C" void kernel_launch(void* const* d_in, const int* in_sizes, int n_in,
                              void* d_out, int out_size, void* d_ws, size_t ws_size,
                              hipStream_t stream) {
    const float* X  = (const float*)d_in[0];
    const float* W1 = (const float*)d_in[1];
    const float* b1 = (const float*)d_in[2];
    const float* W2 = (const float*)d_in[3];
    const float* b2 = (const float*)d_in[4];
    const int*   ei = (const int*)d_in[5];
    const int N = in_sizes[0] / DD;          // 100000
    const int E = in_sizes[5] / 2;           // 640000
    const int* row = ei;
    const int* col = ei + E;

    // -------- workspace carve-up --------
    char* p = (char*)d_ws;
    auto carve = [&](size_t bytes) { char* q = p; p += (bytes + 255) & ~(size_t)255; return q; };
    int*            cnt    = (int*)           carve((size_t)N * 4);
    int*            rowptr = (int*)           carve((size_t)(N + 1) * 4);
    int*            cursor = (int*)           carve((size_t)N * 4);
    int*            part   = (int*)           carve(1024 * 4);
    int*            srow   = (int*)           carve((size_t)E * 4);
    float*          dis    = (float*)         carve((size_t)N * 4);
    unsigned short* xw     = (unsigned short*)carve((size_t)N * DD * 2);   // bf16
    unsigned short* h1     = (unsigned short*)d_out;                       // bf16 scratch in d_out

    const int B = 256;
    const int NBLK = (N + 255) / 256;        // scan blocks
    const int gemm_grid  = (N + 63) / 64;    // 1563
    const int count_grid = (E + B - 1) / B;  // 2500
    const int agg_grid   = (N + 15) / 16;

    // -------- fused: GEMM1 (X fp32 -> xw bf16) + edge count histogram --------
    hipMemsetAsync(cnt, 0, (size_t)N * 4, stream);
    k_gemm_mfma<false, true><<<gemm_grid + count_grid, B, 0, stream>>>(
        X, W1, xw, N, gemm_grid, col, cnt, E);

    // -------- CSR build --------
    k_part<<<NBLK, B, 0, stream>>>(cnt, part, N);
    k_scanpart<<<1, 1024, 0, stream>>>(part, NBLK);
    k_apply<<<NBLK, B, 0, stream>>>(cnt, part, rowptr, cursor, dis, N);
    k_permute<<<count_grid, B, 0, stream>>>(row, col, cursor, srow, E);

    // ---- layer 1 aggregate ----
    k_agg<true><<<agg_grid, B, 0, stream>>>(rowptr, srow, dis, xw, b1, h1, N);

    // ---- layer 2 ----  (h1 bf16 lives in d_out; GEMM2 consumes it before AGG2 overwrites)
    k_gemm_mfma<true, false><<<gemm_grid, B, 0, stream>>>(
        h1, W2, xw, N, gemm_grid, nullptr, nullptr, 0);
    k_agg<false><<<agg_grid, B, 0, stream>>>(rowptr, srow, dis, xw, b2, d_out, N);
}

// Round 6
// 174.367 us; speedup vs baseline: 13.8734x; 1.0053x over previous
//
#include <hip/hip_runtime.h>

#define DD 128

typedef short bf16x8 __attribute__((ext_vector_type(8)));
typedef float f32x4 __attribute__((ext_vector_type(4)));

__device__ __forceinline__ unsigned short f2bf(float f) {   // fp32 -> bf16, RNE
    unsigned int u = __builtin_bit_cast(unsigned int, f);
    u += 0x7fffu + ((u >> 16) & 1u);
    return (unsigned short)(u >> 16);
}
__device__ __forceinline__ float bflo(unsigned int u) { return __builtin_bit_cast(float, u << 16); }
__device__ __forceinline__ float bfhi(unsigned int u) { return __builtin_bit_cast(float, u & 0xffff0000u); }

// ---------------- scan phases ----------------
__global__ __launch_bounds__(256) void k_part(const int* __restrict__ cnt,
                                              int* __restrict__ part, int n) {
    __shared__ int s[256];
    int t = threadIdx.x;
    int i = blockIdx.x * 256 + t;
    s[t] = (i < n) ? cnt[i] : 0;
    __syncthreads();
    for (int off = 128; off > 0; off >>= 1) {
        if (t < off) s[t] += s[t + off];
        __syncthreads();
    }
    if (t == 0) part[blockIdx.x] = s[0];
}

__global__ __launch_bounds__(1024) void k_scanpart(int* __restrict__ part, int nblk) {
    __shared__ int s[1024];
    int t = threadIdx.x;
    int v = (t < nblk) ? part[t] : 0;
    s[t] = v;
    __syncthreads();
    for (int off = 1; off < 1024; off <<= 1) {
        int u = (t >= off) ? s[t - off] : 0;
        __syncthreads();
        s[t] += u;
        __syncthreads();
    }
    if (t < nblk) part[t] = s[t] - v;   // exclusive
}

__global__ __launch_bounds__(256) void k_apply(const int* __restrict__ cnt,
                                               const int* __restrict__ part,
                                               int* __restrict__ rowptr,
                                               int* __restrict__ cursor,
                                               float* __restrict__ dis, int n) {
    __shared__ int s[256];
    int t = threadIdx.x;
    int i = blockIdx.x * 256 + t;
    int c = (i < n) ? cnt[i] : 0;
    s[t] = c;
    __syncthreads();
    for (int off = 1; off < 256; off <<= 1) {
        int u = (t >= off) ? s[t - off] : 0;
        __syncthreads();
        s[t] += u;
        __syncthreads();
    }
    int base = part[blockIdx.x] + s[t] - c;
    if (i < n) {
        rowptr[i] = base;
        cursor[i] = base;
        dis[i] = rsqrtf((float)c + 1.0f);
        if (i == n - 1) rowptr[n] = base + c;
    }
}

// ---------------- permute: srow only (norm recomputed in agg) ----------------
__global__ void k_permute(const int* __restrict__ row, const int* __restrict__ col,
                          int* __restrict__ cursor, int* __restrict__ srow, int E) {
    int e = blockIdx.x * blockDim.x + threadIdx.x;
    if (e >= E) return;
    int p = atomicAdd(&cursor[col[e]], 1);
    srow[p] = row[e];
}

// ---------------- MFMA GEMM: Y(bf16) = X @ W^T  (+ optional fused edge count) ----------------
// 512 threads = 8 waves, 128 rows/block. Wave = 16 rows x 128 cols.
// Operand-swapped MFMA: D = mfma(W_frag, X_frag) -> lane l, reg r holds
// Y[r0 + (l&15)][jt*16 + (l>>4)*4 + r]  => 4 consecutive cols/lane, 8B packed stores.
template <bool INBF16, bool FUSE_COUNT>
__global__ __launch_bounds__(512) void k_gemm_mfma(const void* __restrict__ Xv,
                                                   const float* __restrict__ W,
                                                   unsigned short* __restrict__ Y,
                                                   int nrows, int gemm_blocks,
                                                   const int* __restrict__ col,
                                                   int* __restrict__ cnt, int E) {
    __shared__ unsigned short Ws[128 * 128];   // 32 KB, 16B-chunk XOR swizzle
    const int t = threadIdx.x;

    if (FUSE_COUNT && blockIdx.x >= gemm_blocks) {
        int e = (blockIdx.x - gemm_blocks) * 512 + t;
        if (e < E) atomicAdd(&cnt[col[e]], 1);
        return;
    }

    // stage W: fp32 -> bf16, swizzled. chunk' = chunk ^ (row & 15); 2048 chunks / 512 thr = 4
    #pragma unroll
    for (int i = 0; i < 4; ++i) {
        int g   = i * 512 + t;        // 16B-chunk id, 0..2047
        int row = g >> 4, ch = g & 15;
        const float* src = W + row * 128 + ch * 8;
        float4 f0 = *(const float4*)src;
        float4 f1 = *(const float4*)(src + 4);
        unsigned short u[8] = { f2bf(f0.x), f2bf(f0.y), f2bf(f0.z), f2bf(f0.w),
                                f2bf(f1.x), f2bf(f1.y), f2bf(f1.z), f2bf(f1.w) };
        int dst = row * 128 + ((ch ^ (row & 15)) << 3);
        *(uint4*)&Ws[dst] = *(const uint4*)u;
    }
    __syncthreads();

    const int wid  = t >> 6;          // 0..7
    const int lane = t & 63;
    const int lr   = lane & 15;
    const int lk   = lane >> 4;
    const long r0  = (long)blockIdx.x * 128 + wid * 16;

    long arow = r0 + lr;
    bool rowok = arow < nrows;
    if (!rowok) arow = nrows - 1;     // clamp loads; stores guarded

    f32x4 acc[8] = {};

    #pragma unroll
    for (int kc = 0; kc < 4; ++kc) {
        bf16x8 af;
        if (INBF16) {
            const unsigned short* ap = (const unsigned short*)Xv + arow * 128 + kc * 32 + lk * 8;
            af = *(const bf16x8*)ap;
        } else {
            const float* ap = (const float*)Xv + arow * 128 + kc * 32 + lk * 8;
            float4 a0 = *(const float4*)ap;
            float4 a1 = *(const float4*)(ap + 4);
            af[0] = (short)f2bf(a0.x); af[1] = (short)f2bf(a0.y);
            af[2] = (short)f2bf(a0.z); af[3] = (short)f2bf(a0.w);
            af[4] = (short)f2bf(a1.x); af[5] = (short)f2bf(a1.y);
            af[6] = (short)f2bf(a1.z); af[7] = (short)f2bf(a1.w);
        }
        #pragma unroll
        for (int jt = 0; jt < 8; ++jt) {
            int j  = jt * 16 + lr;
            int ch = (kc * 4 + lk) ^ lr;
            const bf16x8* bp = (const bf16x8*)&Ws[j * 128 + (ch << 3)];
            // swapped operands: A = W-frag, B = X-frag
            acc[jt] = __builtin_amdgcn_mfma_f32_16x16x32_bf16(*bp, af, acc[jt], 0, 0, 0);
        }
    }

    if (rowok) {
        unsigned short* yp = Y + arow * 128 + lk * 4;
        #pragma unroll
        for (int jt = 0; jt < 8; ++jt) {
            unsigned int d0 = (unsigned int)f2bf(acc[jt][0]) | ((unsigned int)f2bf(acc[jt][1]) << 16);
            unsigned int d1 = (unsigned int)f2bf(acc[jt][2]) | ((unsigned int)f2bf(acc[jt][3]) << 16);
            uint2 u; u.x = d0; u.y = d1;
            *(uint2*)(yp + jt * 16) = u;
        }
    }
}

// ---------------- gather-aggregate + self-loop + bias + relu ----------------
// 16 lanes/node, 8 bf16 cols per lane (uint4 = 16B gather); norm computed in-loop
__device__ __forceinline__ void fma8(float* acc, float nm, uint4 q) {
    acc[0] += nm * bflo(q.x); acc[1] += nm * bfhi(q.x);
    acc[2] += nm * bflo(q.y); acc[3] += nm * bfhi(q.y);
    acc[4] += nm * bflo(q.z); acc[5] += nm * bfhi(q.z);
    acc[6] += nm * bflo(q.w); acc[7] += nm * bfhi(q.w);
}

template <bool OUTBF16>
__global__ __launch_bounds__(256) void k_agg(const int* __restrict__ rowptr,
                                             const int* __restrict__ srow,
                                             const float* __restrict__ dis,
                                             const unsigned short* __restrict__ xw,
                                             const float* __restrict__ b,
                                             void* __restrict__ outv, int n) {
    int v = blockIdx.x * 16 + (threadIdx.x >> 4);
    if (v >= n) return;
    int c = (threadIdx.x & 15) * 8;

    float dv = dis[v], s = dv * dv;
    float acc[8] = {};
    fma8(acc, s, *(const uint4*)(xw + (long)v * 128 + c));   // self-loop term

    int e0 = rowptr[v], e1 = rowptr[v + 1];
    int e = e0;
    for (; e + 4 <= e1; e += 4) {
        int   r1 = srow[e],     r2 = srow[e + 1];
        int   r3 = srow[e + 2], r4 = srow[e + 3];
        float n1 = dis[r1] * dv, n2 = dis[r2] * dv;
        float n3 = dis[r3] * dv, n4 = dis[r4] * dv;
        uint4 q1 = *(const uint4*)(xw + (long)r1 * 128 + c);
        uint4 q2 = *(const uint4*)(xw + (long)r2 * 128 + c);
        uint4 q3 = *(const uint4*)(xw + (long)r3 * 128 + c);
        uint4 q4 = *(const uint4*)(xw + (long)r4 * 128 + c);
        fma8(acc, n1, q1);
        fma8(acc, n2, q2);
        fma8(acc, n3, q3);
        fma8(acc, n4, q4);
    }
    for (; e < e1; ++e) {
        int   r1 = srow[e];
        float n1 = dis[r1] * dv;
        fma8(acc, n1, *(const uint4*)(xw + (long)r1 * 128 + c));
    }

    float4 b0 = *(const float4*)(b + c);
    float4 b1 = *(const float4*)(b + c + 4);
    float o[8];
    o[0] = fmaxf(acc[0] + b0.x, 0.0f); o[1] = fmaxf(acc[1] + b0.y, 0.0f);
    o[2] = fmaxf(acc[2] + b0.z, 0.0f); o[3] = fmaxf(acc[3] + b0.w, 0.0f);
    o[4] = fmaxf(acc[4] + b1.x, 0.0f); o[5] = fmaxf(acc[5] + b1.y, 0.0f);
    o[6] = fmaxf(acc[6] + b1.z, 0.0f); o[7] = fmaxf(acc[7] + b1.w, 0.0f);

    if (OUTBF16) {
        unsigned int p[4];
        p[0] = (unsigned int)f2bf(o[0]) | ((unsigned int)f2bf(o[1]) << 16);
        p[1] = (unsigned int)f2bf(o[2]) | ((unsigned int)f2bf(o[3]) << 16);
        p[2] = (unsigned int)f2bf(o[4]) | ((unsigned int)f2bf(o[5]) << 16);
        p[3] = (unsigned int)f2bf(o[6]) | ((unsigned int)f2bf(o[7]) << 16);
        *(uint4*)((unsigned short*)outv + (long)v * 128 + c) = *(const uint4*)p;
    } else {
        float* op = (float*)outv + (long)v * 128 + c;
        *(float4*)op       = make_float4(o[0], o[1], o[2], o[3]);
        *(float4*)(op + 4) = make_float4(o[4], o[5], o[6], o[7]);
    }
}

extern "C" void kernel_launch(void* const* d_in, const int* in_sizes, int n_in,
                              void* d_out, int out_size, void* d_ws, size_t ws_size,
                              hipStream_t stream) {
    const float* X  = (const float*)d_in[0];
    const float* W1 = (const float*)d_in[1];
    const float* b1 = (const float*)d_in[2];
    const float* W2 = (const float*)d_in[3];
    const float* b2 = (const float*)d_in[4];
    const int*   ei = (const int*)d_in[5];
    const int N = in_sizes[0] / DD;          // 100000
    const int E = in_sizes[5] / 2;           // 640000
    const int* row = ei;
    const int* col = ei + E;

    // -------- workspace carve-up --------
    char* p = (char*)d_ws;
    auto carve = [&](size_t bytes) { char* q = p; p += (bytes + 255) & ~(size_t)255; return q; };
    int*            cnt    = (int*)           carve((size_t)N * 4);
    int*            rowptr = (int*)           carve((size_t)(N + 1) * 4);
    int*            cursor = (int*)           carve((size_t)N * 4);
    int*            part   = (int*)           carve(1024 * 4);
    int*            srow   = (int*)           carve((size_t)E * 4);
    float*          dis    = (float*)         carve((size_t)N * 4);
    unsigned short* xw     = (unsigned short*)carve((size_t)N * DD * 2);   // bf16
    unsigned short* h1     = (unsigned short*)d_out;                       // bf16 scratch in d_out

    const int NBLK = (N + 255) / 256;              // scan blocks
    const int gemm_grid  = (N + 127) / 128;        // 782 (512-thread blocks)
    const int count_grid = (E + 511) / 512;        // 1250
    const int perm_grid  = (E + 255) / 256;
    const int agg_grid   = (N + 15) / 16;

    // -------- fused: GEMM1 (X fp32 -> xw bf16) + edge count histogram --------
    hipMemsetAsync(cnt, 0, (size_t)N * 4, stream);
    k_gemm_mfma<false, true><<<gemm_grid + count_grid, 512, 0, stream>>>(
        X, W1, xw, N, gemm_grid, col, cnt, E);

    // -------- CSR build --------
    k_part<<<NBLK, 256, 0, stream>>>(cnt, part, N);
    k_scanpart<<<1, 1024, 0, stream>>>(part, NBLK);
    k_apply<<<NBLK, 256, 0, stream>>>(cnt, part, rowptr, cursor, dis, N);
    k_permute<<<perm_grid, 256, 0, stream>>>(row, col, cursor, srow, E);

    // ---- layer 1 aggregate ----
    k_agg<true><<<agg_grid, 256, 0, stream>>>(rowptr, srow, dis, xw, b1, h1, N);

    // ---- layer 2 ----  (h1 bf16 lives in d_out; GEMM2 consumes it before AGG2 overwrites)
    k_gemm_mfma<true, false><<<gemm_grid, 512, 0, stream>>>(
        h1, W2, xw, N, gemm_grid, nullptr, nullptr, 0);
    k_agg<false><<<agg_grid, 256, 0, stream>>>(rowptr, srow, dis, xw, b2, d_out, N);
}